// Round 6
// baseline (216.090 us; speedup 1.0000x reference)
//
#include <hip/hip_runtime.h>

#define TT 2048
#define DM 1152
#define NHEAD 16
#define HDIM 72
#define HDP 96
#define HDV 80
#define KSPLIT 2

typedef __attribute__((ext_vector_type(8))) __bf16 bf16x8;
typedef __attribute__((ext_vector_type(4))) float f32x4;
typedef unsigned short u16;
typedef unsigned int u32;

__device__ inline u16 f2bf(float f){
  u32 u = __builtin_bit_cast(u32, f);
  return (u16)((u + 0x7FFFu + ((u >> 16) & 1u)) >> 16);
}
__device__ inline float bf2f(u16 v){
  return __builtin_bit_cast(float, ((u32)v) << 16);
}
__device__ inline bf16x8 ldb8(const u16* p){
  uint4 u = *(const uint4*)p;
  return __builtin_bit_cast(bf16x8, u);
}
__device__ inline f32x4 mfma16(bf16x8 a, bf16x8 b, f32x4 c){
  return __builtin_amdgcn_mfma_f32_16x16x32_bf16(a, b, c, 0, 0, 0);
}
// async global->LDS, 16B per lane, dest = wave-uniform base + lane*16
__device__ inline void gload_lds16(const u16* g, u16* l){
  __builtin_amdgcn_global_load_lds(
      (const __attribute__((address_space(1))) void*)g,
      (__attribute__((address_space(3))) void*)l, 16, 0, 0);
}

// ---- fp32 -> bf16 conversion for hidden + 4 weights; segment ids; pad-zeroing ----
__global__ void k_convert(const float* hid, const float* wq, const float* wk,
                          const float* wv, const float* wo, const int* cu,
                          u16* hb, u16* wqb, u16* wkb, u16* wvb, u16* wob,
                          u16* qhb, u16* khb, int* seg)
{
  long i = (long)blockIdx.x * blockDim.x + threadIdx.x;
  const long NHID = (long)TT * DM;
  const long NW = (long)DM * DM;
  const long NCV = NHID + 4*NW;
  if (i < NHID) {
    hb[i] = f2bf(hid[i]);
  } else if (i < NCV) {
    long j = i - NHID;
    int w = (int)(j / NW);
    long o = j - (long)w * NW;
    const float* src = (w==0)?wq:(w==1)?wk:(w==2)?wv:wo;
    u16* dst = (w==0)?wqb:(w==1)?wkb:(w==2)?wvb:wob;
    dst[o] = f2bf(src[o]);
  } else {
    // zero the dh padding (u16 cols 72..95 = u32 cols 36..47) of qhb/khb
    long j = i - NCV;                      // [0, 2*16*2048*12)
    const long PER = (long)NHEAD*TT*12;
    int arr = (int)(j / PER);
    long r = j - (long)arr*PER;
    long th = r / 12;                      // h*TT + t
    int c = (int)(r - th*12);
    ((u32*)(arr ? khb : qhb))[th*48 + 36 + c] = 0u;
  }
  if (i < TT) {
    int c = 0;
    for (int e = 0; e < 9; ++e) c += (cu[e] <= (int)i);
    seg[i] = c - 1;
  }
}

// ---- 128x128-tile GEMM body: C = (A(2048xK) @ W(NxK)^T + bias) * oscale ----
// mode 0: bf16 scatter to (H, T, 96);  mode 2: bf16 scatter to (H, 80, T)
__device__ __forceinline__ void gemm128_body(const u16* __restrict__ A,
                                             const u16* __restrict__ W,
                                             const float* __restrict__ bias,
                                             void* out, int mode, float oscale)
{
  __shared__ __align__(16) u16 As[128*32];
  __shared__ __align__(16) u16 Bs[128*32];
  int tid = threadIdx.x;
  int lane = tid & 63, wid = tid >> 6;
  int l15 = lane & 15, quad = lane >> 4;
  int bm = blockIdx.x * 128, bn = blockIdx.y * 128;
  int wm = (wid>>1)*64, wn = (wid&1)*64;
  f32x4 acc[4][4] = {};
  const u16* ga = A + (long)(bm + (tid>>2))*DM + (tid&3)*8;
  const u16* gb = W + (long)(bn + (tid>>2))*DM + (tid&3)*8;
  u16* lA = As + wid*512;   // wave-uniform base (1024 B per wave)
  u16* lB = Bs + wid*512;
  for (int k0 = 0; k0 < DM; k0 += 32) {
    gload_lds16(ga + k0,          lA);
    gload_lds16(ga + k0 + 64*DM,  lA + 2048);
    gload_lds16(gb + k0,          lB);
    gload_lds16(gb + k0 + 64*DM,  lB + 2048);
    __syncthreads();
    bf16x8 af[4], bfr[4];
    for (int i=0;i<4;i++) af[i]  = ldb8(As + (wm + i*16 + l15)*32 + quad*8);
    for (int i=0;i<4;i++) bfr[i] = ldb8(Bs + (wn + i*16 + l15)*32 + quad*8);
    for (int mi=0;mi<4;mi++)
      for (int ni=0;ni<4;ni++)
        acc[mi][ni] = mfma16(af[mi], bfr[ni], acc[mi][ni]);
    __syncthreads();
  }
  for (int ni=0;ni<4;ni++){
    int n = bn + wn + ni*16 + l15;
    float bv_ = bias[n];
    int h = n / HDIM, dh = n - (n / HDIM)*HDIM;
    for (int mi=0;mi<4;mi++){
      int m0 = bm + wm + mi*16 + quad*4;
      for (int r=0;r<4;r++){
        float v = (acc[mi][ni][r] + bv_) * oscale;
        int m = m0 + r;
        if (mode == 0) {
          ((u16*)out)[((long)(h*TT + m))*HDP + dh] = f2bf(v);
        } else {
          ((u16*)out)[((long)(h*HDV + dh))*TT + m] = f2bf(v);
        }
      }
    }
  }
}

__global__ __launch_bounds__(256) void k_gemm_qkv(const u16* __restrict__ A,
    const u16* __restrict__ Wq, const u16* __restrict__ Wk, const u16* __restrict__ Wv,
    const float* __restrict__ bq, const float* __restrict__ bk, const float* __restrict__ bv,
    u16* oq, u16* ok, u16* ov)
{
  const float scale = 0.11785113019775793f; // 72^-0.5, folded into q
  int z = blockIdx.z;
  if (z == 0)      gemm128_body(A, Wq, bq, oq, 0, scale);
  else if (z == 1) gemm128_body(A, Wk, bk, ok, 0, 1.0f);
  else             gemm128_body(A, Wv, bv, ov, 2, 1.0f);
}

// ---- O-projection: 64x128 tiles, fp32 out ----
__global__ __launch_bounds__(256) void k_gemm_o(const u16* __restrict__ A,
    const u16* __restrict__ W, const float* __restrict__ bias, float* out)
{
  __shared__ __align__(16) u16 As[64*32];
  __shared__ __align__(16) u16 Bs[128*32];
  int tid = threadIdx.x;
  int lane = tid & 63, wid = tid >> 6;
  int l15 = lane & 15, quad = lane >> 4;
  int bm = blockIdx.x * 64, bn = blockIdx.y * 128;
  int wm = (wid>>1)*32, wn = (wid&1)*64;
  f32x4 acc[2][4] = {};
  const u16* ga = A + (long)(bm + (tid>>2))*DM + (tid&3)*8;
  const u16* gb = W + (long)(bn + (tid>>2))*DM + (tid&3)*8;
  u16* lA = As + wid*512;
  u16* lB = Bs + wid*512;
  for (int k0 = 0; k0 < DM; k0 += 32) {
    gload_lds16(ga + k0,          lA);
    gload_lds16(gb + k0,          lB);
    gload_lds16(gb + k0 + 64*DM,  lB + 2048);
    __syncthreads();
    bf16x8 af[2], bfr[4];
    for (int i=0;i<2;i++) af[i]  = ldb8(As + (wm + i*16 + l15)*32 + quad*8);
    for (int i=0;i<4;i++) bfr[i] = ldb8(Bs + (wn + i*16 + l15)*32 + quad*8);
    for (int mi=0;mi<2;mi++)
      for (int ni=0;ni<4;ni++)
        acc[mi][ni] = mfma16(af[mi], bfr[ni], acc[mi][ni]);
    __syncthreads();
  }
  for (int ni=0;ni<4;ni++){
    int n = bn + wn + ni*16 + l15;
    float bv_ = bias[n];
    for (int mi=0;mi<2;mi++){
      int m0 = bm + wm + mi*16 + quad*4;
      for (int r=0;r<4;r++)
        out[(long)(m0 + r)*DM + n] = acc[mi][ni][r] + bv_;
    }
  }
}

// ---- RoPE in-place on q,k padded layouts ----
__global__ void k_rope(u16* qh, u16* kh, const float* __restrict__ cosb,
                       const float* __restrict__ sinb)
{
  int i = blockIdx.x * blockDim.x + threadIdx.x;
  const int total = 2 * NHEAD * TT * 36;
  if (i >= total) return;
  int d = i % 36; int rest = i / 36;
  int t = rest % TT; rest /= TT;
  int h = rest % NHEAD; int qk = rest / NHEAD;
  u16* base = (qk ? kh : qh) + ((long)h*TT + t)*HDP;
  float x1 = bf2f(base[d]), x2 = bf2f(base[d+36]);
  float c = cosb[t*HDIM + d], s = sinb[t*HDIM + d];
  base[d]    = f2bf(x1*c - x2*s);
  base[d+36] = f2bf(x2*c + x1*s);
}

// ---- flash attention, fixed-max softmax, split-K, BARRIER-FREE ----
// K B-fragments loaded straight from global (L2-served); pbuf is wave-private.
__global__ __launch_bounds__(256, 4) void k_attn(const u16* __restrict__ qh,
                                                 const u16* __restrict__ kh,
                                                 const u16* __restrict__ vT,
                                                 const int* __restrict__ seg,
                                                 const int* __restrict__ cu,
                                                 float* __restrict__ pacc,
                                                 float* __restrict__ plsum)
{
  __shared__ __align__(16) u16 pbuf[4][16][72];    // wave-private slices, padded rows
  int h = blockIdx.y;
  int z = blockIdx.z;
  int tid = threadIdx.x, lane = tid & 63, wid = tid >> 6;
  int l15 = lane & 15, quad = lane >> 4;
  int qb0 = blockIdx.x * 64;
  int qbase = qb0 + wid*16;

  const u16* qp = qh + ((long)h*TT + qbase + l15)*HDP + quad*8;
  bf16x8 qf0 = ldb8(qp), qf1 = ldb8(qp+32), qf2 = ldb8(qp+64);
  // per-row key ranges replace per-tile seg[] gathers
  int lo[4], hi[4];
  for (int r=0;r<4;r++){
    int sq = seg[qbase + quad*4 + r];
    lo[r] = cu[sq]; hi[r] = cu[sq+1];
  }
  f32x4 acc[5] = {};
  float lsum[4] = {0.f, 0.f, 0.f, 0.f};

  int s_begin = cu[seg[qb0]] & ~63;
  int s_end = cu[seg[qb0 + 63] + 1];
  int nt = (s_end - s_begin + 63) >> 6;
  int nt0 = (nt + 1) >> 1;
  int it_lo = z ? nt0 : 0;
  int it_hi = z ? nt : nt0;

  const u16* kbase = kh + (long)h*TT*HDP;
  const u16* vbase = vT + ((long)h*HDV + l15)*TT + quad*8;

  for (int it = it_lo; it < it_hi; ++it) {
    int s0 = s_begin + it*64;
    // K fragments: B[n=key, k=dh] direct from global — 12 independent 16B loads
    const u16* kp = kbase + (long)(s0 + l15)*HDP + quad*8;
    bf16x8 kf[4][3];
    for (int j=0;j<4;j++)
      for (int c=0;c<3;c++)
        kf[j][c] = ldb8(kp + j*16*HDP + c*32);
    f32x4 sc[4] = {};
    for (int j=0;j<4;j++){
      sc[j] = mfma16(qf0, kf[j][0], sc[j]);
      sc[j] = mfma16(qf1, kf[j][1], sc[j]);
      sc[j] = mfma16(qf2, kf[j][2], sc[j]);
    }
    float p[4][4];
    for (int j=0;j<4;j++){
      int kidx = s0 + j*16 + l15;
      for (int r=0;r<4;r++){
        bool in = (kidx >= lo[r]) && (kidx < hi[r]);
        p[j][r] = in ? __expf(sc[j][r]) : 0.f;
        lsum[r] += p[j][r];
      }
    }
    // P: C-layout -> LDS (wave-private, no barrier) -> A-layout
    for (int j=0;j<4;j++)
      for (int r=0;r<4;r++)
        pbuf[wid][quad*4+r][j*16+l15] = f2bf(p[j][r]);
    bf16x8 pf0 = ldb8(&pbuf[wid][l15][quad*8]);
    bf16x8 pf1 = ldb8(&pbuf[wid][l15][32 + quad*8]);
    const u16* vp = vbase + s0;
    for (int n=0;n<5;n++){
      bf16x8 vf0 = ldb8(vp + (long)n*16*TT);
      bf16x8 vf1 = ldb8(vp + (long)n*16*TT + 32);
      acc[n] = mfma16(pf0, vf0, acc[n]);
      acc[n] = mfma16(pf1, vf1, acc[n]);
    }
  }
  // reduce lsum across the 16 key-lanes
  for (int off=1; off<16; off<<=1)
    for (int r=0;r<4;r++)
      lsum[r] += __shfl_xor(lsum[r], off, 64);
  // write unnormalized partials
  for (int n=0;n<5;n++){
    int dh = n*16 + l15;
    for (int r=0;r<4;r++){
      int t = qbase + quad*4 + r;
      pacc[(((long)z*TT + t)*NHEAD + h)*HDV + dh] = acc[n][r];
    }
  }
  if (l15 == 0){
    for (int r=0;r<4;r++){
      int t = qbase + quad*4 + r;
      plsum[((long)z*TT + t)*NHEAD + h] = lsum[r];
    }
  }
}

// ---- combine split-K partials -> aob (T, DM) bf16 ----
__global__ void k_combine(const float* __restrict__ pacc,
                          const float* __restrict__ plsum,
                          u16* __restrict__ ao)
{
  int i = blockIdx.x*blockDim.x + threadIdx.x;
  const int total = TT*NHEAD*HDIM;
  if (i >= total) return;
  int dh = i % HDIM; int rest = i / HDIM;
  int h = rest % NHEAD; int t = rest / NHEAD;
  long i0 = ((long)t*NHEAD + h)*HDV + dh;
  float a = pacc[i0] + pacc[(long)TT*NHEAD*HDV + i0];
  float l = plsum[t*NHEAD + h] + plsum[TT*NHEAD + t*NHEAD + h];
  ao[(long)t*DM + h*HDIM + dh] = f2bf(a / l);
}

extern "C" void kernel_launch(void* const* d_in, const int* in_sizes, int n_in,
                              void* d_out, int out_size, void* d_ws, size_t ws_size,
                              hipStream_t stream)
{
  const float* hid  = (const float*)d_in[0];
  const int*   cu   = (const int*)d_in[1];
  const float* cosb = (const float*)d_in[2];
  const float* sinb = (const float*)d_in[3];
  const float* wq   = (const float*)d_in[4];
  const float* bq   = (const float*)d_in[5];
  const float* wk   = (const float*)d_in[6];
  const float* bk   = (const float*)d_in[7];
  const float* wv   = (const float*)d_in[8];
  const float* bv   = (const float*)d_in[9];
  const float* wo   = (const float*)d_in[10];
  const float* bo   = (const float*)d_in[11];

  char* ws = (char*)d_ws;
  u16* hb  = (u16*)ws; ws += (long)TT*DM*2;
  u16* wqb = (u16*)ws; ws += (long)DM*DM*2;
  u16* wkb = (u16*)ws; ws += (long)DM*DM*2;
  u16* wvb = (u16*)ws; ws += (long)DM*DM*2;
  u16* wob = (u16*)ws; ws += (long)DM*DM*2;
  u16* qhb = (u16*)ws; ws += (long)NHEAD*TT*HDP*2;
  u16* khb = (u16*)ws; ws += (long)NHEAD*TT*HDP*2;
  u16* vTb = (u16*)ws; ws += (long)NHEAD*HDV*TT*2;
  u16* aob = (u16*)ws; ws += (long)TT*DM*2;
  int* seg = (int*)ws; ws += (long)TT*4;
  float* pacc  = (float*)ws; ws += (long)KSPLIT*TT*NHEAD*HDV*4;
  float* plsum = (float*)ws; ws += (long)KSPLIT*TT*NHEAD*4;

  long nconv = (long)TT*DM + 4L*DM*DM + 2L*NHEAD*TT*12;
  k_convert<<<dim3((nconv + 255)/256), 256, 0, stream>>>(
      hid, wq, wk, wv, wo, cu, hb, wqb, wkb, wvb, wob, qhb, khb, seg);

  dim3 gqkv(TT/128, DM/128, 3);
  k_gemm_qkv<<<gqkv, 256, 0, stream>>>(hb, wqb, wkb, wvb, bq, bk, bv, qhb, khb, vTb);

  int nrope = 2*NHEAD*TT*36;
  k_rope<<<dim3((nrope + 255)/256), 256, 0, stream>>>(qhb, khb, cosb, sinb);

  dim3 ga(TT/64, NHEAD, KSPLIT);
  k_attn<<<ga, 256, 0, stream>>>(qhb, khb, vTb, seg, cu, pacc, plsum);

  int ncomb = TT*NHEAD*HDIM;
  k_combine<<<dim3((ncomb + 255)/256), 256, 0, stream>>>(pacc, plsum, aob);

  dim3 go(TT/64, DM/128);
  k_gemm_o<<<go, 256, 0, stream>>>(aob, wob, bo, (float*)d_out);
}

// Round 7
// 203.173 us; speedup vs baseline: 1.0636x; 1.0636x over previous
//
#include <hip/hip_runtime.h>

#define TT 2048
#define DM 1152
#define NHEAD 16
#define HDIM 72
#define HDP 96
#define HDV 80
#define KSPLIT 2

typedef __attribute__((ext_vector_type(8))) __bf16 bf16x8;
typedef __attribute__((ext_vector_type(4))) float f32x4;
typedef unsigned short u16;
typedef unsigned int u32;
typedef __attribute__((ext_vector_type(4))) u16 u16x4;

__device__ inline u16 f2bf(float f){
  u32 u = __builtin_bit_cast(u32, f);
  return (u16)((u + 0x7FFFu + ((u >> 16) & 1u)) >> 16);
}
__device__ inline float bf2f(u16 v){
  return __builtin_bit_cast(float, ((u32)v) << 16);
}
__device__ inline bf16x8 ldb8(const u16* p){
  uint4 u = *(const uint4*)p;
  return __builtin_bit_cast(bf16x8, u);
}
__device__ inline f32x4 mfma16(bf16x8 a, bf16x8 b, f32x4 c){
  return __builtin_amdgcn_mfma_f32_16x16x32_bf16(a, b, c, 0, 0, 0);
}
// async global->LDS, 16B per lane, dest = wave-uniform base + lane*16
__device__ inline void gload_lds16(const u16* g, u16* l){
  __builtin_amdgcn_global_load_lds(
      (const __attribute__((address_space(1))) void*)g,
      (__attribute__((address_space(3))) void*)l, 16, 0, 0);
}

// ---- fp32 -> bf16 conversion (float4-vectorized); segment ids; pad-zeroing ----
__global__ void k_convert(const float* hid, const float* wq, const float* wk,
                          const float* wv, const float* wo, const int* cu,
                          u16* hb, u16* wqb, u16* wkb, u16* wvb, u16* wob,
                          u16* qhb, u16* khb, int* seg)
{
  long i = (long)blockIdx.x * blockDim.x + threadIdx.x;
  const long NHID4 = (long)TT * DM / 4;      // 589824
  const long NW4 = (long)DM * DM / 4;        // 331776
  const long NC4 = NHID4 + 4*NW4;            // 1916928
  if (i < NC4) {
    const float4* src; u16* dst; long o;
    if (i < NHID4) { src = (const float4*)hid; dst = hb; o = i; }
    else {
      long j = i - NHID4;
      int w = (int)(j / NW4);
      o = j - (long)w * NW4;
      src = (const float4*)((w==0)?wq:(w==1)?wk:(w==2)?wv:wo);
      dst = (w==0)?wqb:(w==1)?wkb:(w==2)?wvb:wob;
    }
    float4 v = src[o];
    u16x4 r; r.x = f2bf(v.x); r.y = f2bf(v.y); r.z = f2bf(v.z); r.w = f2bf(v.w);
    *(u16x4*)(dst + o*4) = r;
  } else {
    // zero the dh padding (u16 cols 72..95 = u32 cols 36..47) of qhb/khb
    long j = i - NC4;                        // [0, 2*16*2048*12)
    const long PER = (long)NHEAD*TT*12;
    if (j < 2*PER) {
      int arr = (int)(j / PER);
      long r = j - (long)arr*PER;
      long th = r / 12;                      // h*TT + t
      int c = (int)(r - th*12);
      ((u32*)(arr ? khb : qhb))[th*48 + 36 + c] = 0u;
    }
  }
  if (i < TT) {
    int c = 0;
    for (int e = 0; e < 9; ++e) c += (cu[e] <= (int)i);
    seg[i] = c - 1;
  }
}

// ---- 128x64-tile double-buffered GEMM: C = (A(2048xK) @ W(NxK)^T + bias)*oscale ----
// mode 0: bf16 scatter to (H, T, 96);  mode 2: bf16 scatter to (H, 80, T)
__device__ __forceinline__ void gemm_m128n64(const u16* __restrict__ A,
                                             const u16* __restrict__ W,
                                             const float* __restrict__ bias,
                                             void* out, int mode, float oscale)
{
  __shared__ __align__(16) u16 As[2][128*32];   // 2 x 8 KB
  __shared__ __align__(16) u16 Bs[2][64*32];    // 2 x 4 KB
  int tid = threadIdx.x;
  int lane = tid & 63, wid = tid >> 6;
  int l15 = lane & 15, quad = lane >> 4;
  int bm = blockIdx.x * 128, bn = blockIdx.y * 64;
  int wm = wid*32;
  f32x4 acc[2][4] = {};
  const u16* ga = A + (long)(bm + (tid>>2))*DM + (tid&3)*8;
  const u16* gb = W + (long)(bn + (tid>>2))*DM + (tid&3)*8;
  // preload k-tile 0
  {
    u16* lA = As[0] + wid*512; u16* lB = Bs[0] + wid*512;
    gload_lds16(ga,          lA);
    gload_lds16(ga + 64*DM,  lA + 2048);
    gload_lds16(gb,          lB);
  }
  int cur = 0;
  for (int k0 = 0; k0 < DM; k0 += 32, cur ^= 1) {
    __syncthreads();                   // drains prefetch of buf[cur]
    if (k0 + 32 < DM) {                // prefetch next tile during compute
      u16* lA = As[cur^1] + wid*512; u16* lB = Bs[cur^1] + wid*512;
      gload_lds16(ga + k0 + 32,          lA);
      gload_lds16(ga + k0 + 32 + 64*DM,  lA + 2048);
      gload_lds16(gb + k0 + 32,          lB);
    }
    bf16x8 af[2], bfr[4];
    for (int i=0;i<2;i++) af[i]  = ldb8(As[cur] + (wm + i*16 + l15)*32 + quad*8);
    for (int i=0;i<4;i++) bfr[i] = ldb8(Bs[cur] + (i*16 + l15)*32 + quad*8);
    for (int mi=0;mi<2;mi++)
      for (int ni=0;ni<4;ni++)
        acc[mi][ni] = mfma16(af[mi], bfr[ni], acc[mi][ni]);
  }
  for (int ni=0;ni<4;ni++){
    int n = bn + ni*16 + l15;
    float bv_ = bias[n];
    int h = n / HDIM, dh = n - (n / HDIM)*HDIM;
    for (int mi=0;mi<2;mi++){
      int m0 = bm + wm + mi*16 + quad*4;
      for (int r=0;r<4;r++){
        float v = (acc[mi][ni][r] + bv_) * oscale;
        int m = m0 + r;
        if (mode == 0) {
          ((u16*)out)[((long)(h*TT + m))*HDP + dh] = f2bf(v);
        } else {
          ((u16*)out)[((long)(h*HDV + dh))*TT + m] = f2bf(v);
        }
      }
    }
  }
}

__global__ __launch_bounds__(256, 4) void k_gemm_qkv(const u16* __restrict__ A,
    const u16* __restrict__ Wq, const u16* __restrict__ Wk, const u16* __restrict__ Wv,
    const float* __restrict__ bq, const float* __restrict__ bk, const float* __restrict__ bv,
    u16* oq, u16* ok, u16* ov)
{
  const float scale = 0.11785113019775793f; // 72^-0.5, folded into q
  int z = blockIdx.z;
  if (z == 0)      gemm_m128n64(A, Wq, bq, oq, 0, scale);
  else if (z == 1) gemm_m128n64(A, Wk, bk, ok, 0, 1.0f);
  else             gemm_m128n64(A, Wv, bv, ov, 2, 1.0f);
}

// ---- O-projection: 64x64 tiles, double-buffered, fp32 out ----
__global__ __launch_bounds__(256, 4) void k_gemm_o(const u16* __restrict__ A,
    const u16* __restrict__ W, const float* __restrict__ bias, float* out)
{
  __shared__ __align__(16) u16 As[2][64*32];
  __shared__ __align__(16) u16 Bs[2][64*32];
  int tid = threadIdx.x;
  int lane = tid & 63, wid = tid >> 6;
  int l15 = lane & 15, quad = lane >> 4;
  int bm = blockIdx.x * 64, bn = blockIdx.y * 64;
  int wm = (wid>>1)*32, wn = (wid&1)*32;
  f32x4 acc[2][2] = {};
  const u16* ga = A + (long)(bm + (tid>>2))*DM + (tid&3)*8;
  const u16* gb = W + (long)(bn + (tid>>2))*DM + (tid&3)*8;
  {
    gload_lds16(ga, As[0] + wid*512);
    gload_lds16(gb, Bs[0] + wid*512);
  }
  int cur = 0;
  for (int k0 = 0; k0 < DM; k0 += 32, cur ^= 1) {
    __syncthreads();
    if (k0 + 32 < DM) {
      gload_lds16(ga + k0 + 32, As[cur^1] + wid*512);
      gload_lds16(gb + k0 + 32, Bs[cur^1] + wid*512);
    }
    bf16x8 af[2], bfr[2];
    for (int i=0;i<2;i++) af[i]  = ldb8(As[cur] + (wm + i*16 + l15)*32 + quad*8);
    for (int i=0;i<2;i++) bfr[i] = ldb8(Bs[cur] + (wn + i*16 + l15)*32 + quad*8);
    for (int mi=0;mi<2;mi++)
      for (int ni=0;ni<2;ni++)
        acc[mi][ni] = mfma16(af[mi], bfr[ni], acc[mi][ni]);
  }
  for (int ni=0;ni<2;ni++){
    int n = bn + wn + ni*16 + l15;
    float bv_ = bias[n];
    for (int mi=0;mi<2;mi++){
      int m0 = bm + wm + mi*16 + quad*4;
      for (int r=0;r<4;r++)
        out[(long)(m0 + r)*DM + n] = acc[mi][ni][r] + bv_;
    }
  }
}

// ---- RoPE in-place on q,k padded layouts ----
__global__ void k_rope(u16* qh, u16* kh, const float* __restrict__ cosb,
                       const float* __restrict__ sinb)
{
  int i = blockIdx.x * blockDim.x + threadIdx.x;
  const int total = 2 * NHEAD * TT * 36;
  if (i >= total) return;
  int d = i % 36; int rest = i / 36;
  int t = rest % TT; rest /= TT;
  int h = rest % NHEAD; int qk = rest / NHEAD;
  u16* base = (qk ? kh : qh) + ((long)h*TT + t)*HDP;
  float x1 = bf2f(base[d]), x2 = bf2f(base[d+36]);
  float c = cosb[t*HDIM + d], s = sinb[t*HDIM + d];
  base[d]    = f2bf(x1*c - x2*s);
  base[d+36] = f2bf(x2*c + x1*s);
}

// ---- flash attention: LDS-staged K (double-buffered), fixed-max softmax, split-K ----
__global__ __launch_bounds__(256) void k_attn(const u16* __restrict__ qh,
                                              const u16* __restrict__ kh,
                                              const u16* __restrict__ vT,
                                              const int* __restrict__ seg,
                                              const int* __restrict__ cu,
                                              float* __restrict__ pacc,
                                              float* __restrict__ plsum)
{
  __shared__ __align__(16) u16 Ks[2][64*96];       // 2 x 12 KB double buffer
  __shared__ __align__(16) u16 pbuf[4][16][72];    // padded rows break bank alias
  int h = blockIdx.y;
  int z = blockIdx.z;
  int tid = threadIdx.x, lane = tid & 63, wid = tid >> 6;
  int l15 = lane & 15, quad = lane >> 4;
  int qb0 = blockIdx.x * 64;
  int qbase = qb0 + wid*16;

  const u16* qp = qh + ((long)h*TT + qbase + l15)*HDP + quad*8;
  bf16x8 qf0 = ldb8(qp), qf1 = ldb8(qp+32), qf2 = ldb8(qp+64);
  // per-row key ranges (hoisted mask)
  int lo[4], hi[4];
  for (int r=0;r<4;r++){
    int sq = seg[qbase + quad*4 + r];
    lo[r] = cu[sq]; hi[r] = cu[sq+1];
  }
  f32x4 acc[5] = {};
  float lsum[4] = {0.f, 0.f, 0.f, 0.f};

  int s_begin = cu[seg[qb0]] & ~63;
  int s_end = cu[seg[qb0 + 63] + 1];
  int nt = (s_end - s_begin + 63) >> 6;
  int nt0 = (nt + 1) >> 1;
  int it_lo = z ? nt0 : 0;
  int it_hi = z ? nt : nt0;

  const u16* kbase = kh + (long)h*TT*HDP;
  const u16* vbase = vT + ((long)h*HDV + l15)*TT + quad*8;

  if (it_lo < it_hi) {
    {
      const u16* gk = kbase + (long)(s_begin + it_lo*64)*HDP + tid*8;
      u16* lK = Ks[0] + wid*512;
      gload_lds16(gk,        lK);
      gload_lds16(gk + 2048, lK + 2048);
      gload_lds16(gk + 4096, lK + 4096);
    }
    for (int it = it_lo; it < it_hi; ++it) {
      int s0 = s_begin + it*64;
      int cur = (it - it_lo) & 1;
      __syncthreads();
      if (it + 1 < it_hi) {
        const u16* gk = kbase + (long)(s0 + 64)*HDP + tid*8;
        u16* lK = Ks[cur^1] + wid*512;
        gload_lds16(gk,        lK);
        gload_lds16(gk + 2048, lK + 2048);
        gload_lds16(gk + 4096, lK + 4096);
      }
      f32x4 sc[4] = {};
      for (int j=0;j<4;j++){
        const u16* kp = Ks[cur] + (j*16 + l15)*96 + quad*8;
        sc[j] = mfma16(qf0, ldb8(kp),    sc[j]);
        sc[j] = mfma16(qf1, ldb8(kp+32), sc[j]);
        sc[j] = mfma16(qf2, ldb8(kp+64), sc[j]);
      }
      float p[4][4];
      for (int j=0;j<4;j++){
        int kidx = s0 + j*16 + l15;
        for (int r=0;r<4;r++){
          bool in = (kidx >= lo[r]) && (kidx < hi[r]);
          p[j][r] = in ? __expf(sc[j][r]) : 0.f;
          lsum[r] += p[j][r];
        }
      }
      // P: C-layout -> LDS (wave-private) -> A-layout
      for (int j=0;j<4;j++)
        for (int r=0;r<4;r++)
          pbuf[wid][quad*4+r][j*16+l15] = f2bf(p[j][r]);
      bf16x8 pf0 = ldb8(&pbuf[wid][l15][quad*8]);
      bf16x8 pf1 = ldb8(&pbuf[wid][l15][32 + quad*8]);
      const u16* vp = vbase + s0;
      for (int n=0;n<5;n++){
        bf16x8 vf0 = ldb8(vp + (long)n*16*TT);
        bf16x8 vf1 = ldb8(vp + (long)n*16*TT + 32);
        acc[n] = mfma16(pf0, vf0, acc[n]);
        acc[n] = mfma16(pf1, vf1, acc[n]);
      }
    }
  }
  // reduce lsum across the 16 key-lanes
  for (int off=1; off<16; off<<=1)
    for (int r=0;r<4;r++)
      lsum[r] += __shfl_xor(lsum[r], off, 64);
  // write unnormalized partials
  for (int n=0;n<5;n++){
    int dh = n*16 + l15;
    for (int r=0;r<4;r++){
      int t = qbase + quad*4 + r;
      pacc[(((long)z*TT + t)*NHEAD + h)*HDV + dh] = acc[n][r];
    }
  }
  if (l15 == 0){
    for (int r=0;r<4;r++){
      int t = qbase + quad*4 + r;
      plsum[((long)z*TT + t)*NHEAD + h] = lsum[r];
    }
  }
}

// ---- combine split-K partials -> aob (T, DM) bf16 ----
__global__ void k_combine(const float* __restrict__ pacc,
                          const float* __restrict__ plsum,
                          u16* __restrict__ ao)
{
  int i = blockIdx.x*blockDim.x + threadIdx.x;
  const int total = TT*NHEAD*HDIM;
  if (i >= total) return;
  int dh = i % HDIM; int rest = i / HDIM;
  int h = rest % NHEAD; int t = rest / NHEAD;
  long i0 = ((long)t*NHEAD + h)*HDV + dh;
  float a = pacc[i0] + pacc[(long)TT*NHEAD*HDV + i0];
  float l = plsum[t*NHEAD + h] + plsum[TT*NHEAD + t*NHEAD + h];
  ao[(long)t*DM + h*HDIM + dh] = f2bf(a / l);
}

extern "C" void kernel_launch(void* const* d_in, const int* in_sizes, int n_in,
                              void* d_out, int out_size, void* d_ws, size_t ws_size,
                              hipStream_t stream)
{
  const float* hid  = (const float*)d_in[0];
  const int*   cu   = (const int*)d_in[1];
  const float* cosb = (const float*)d_in[2];
  const float* sinb = (const float*)d_in[3];
  const float* wq   = (const float*)d_in[4];
  const float* bq   = (const float*)d_in[5];
  const float* wk   = (const float*)d_in[6];
  const float* bk   = (const float*)d_in[7];
  const float* wv   = (const float*)d_in[8];
  const float* bv   = (const float*)d_in[9];
  const float* wo   = (const float*)d_in[10];
  const float* bo   = (const float*)d_in[11];

  char* ws = (char*)d_ws;
  u16* hb  = (u16*)ws; ws += (long)TT*DM*2;
  u16* wqb = (u16*)ws; ws += (long)DM*DM*2;
  u16* wkb = (u16*)ws; ws += (long)DM*DM*2;
  u16* wvb = (u16*)ws; ws += (long)DM*DM*2;
  u16* wob = (u16*)ws; ws += (long)DM*DM*2;
  u16* qhb = (u16*)ws; ws += (long)NHEAD*TT*HDP*2;
  u16* khb = (u16*)ws; ws += (long)NHEAD*TT*HDP*2;
  u16* vTb = (u16*)ws; ws += (long)NHEAD*HDV*TT*2;
  u16* aob = (u16*)ws; ws += (long)TT*DM*2;
  int* seg = (int*)ws; ws += (long)TT*4;
  float* pacc  = (float*)ws; ws += (long)KSPLIT*TT*NHEAD*HDV*4;
  float* plsum = (float*)ws; ws += (long)KSPLIT*TT*NHEAD*4;

  long nconv = ((long)TT*DM + 4L*DM*DM)/4 + 2L*NHEAD*TT*12;
  k_convert<<<dim3((nconv + 255)/256), 256, 0, stream>>>(
      hid, wq, wk, wv, wo, cu, hb, wqb, wkb, wvb, wob, qhb, khb, seg);

  dim3 gqkv(TT/128, DM/64, 3);
  k_gemm_qkv<<<gqkv, 256, 0, stream>>>(hb, wqb, wkb, wvb, bq, bk, bv, qhb, khb, vTb);

  int nrope = 2*NHEAD*TT*36;
  k_rope<<<dim3((nrope + 255)/256), 256, 0, stream>>>(qhb, khb, cosb, sinb);

  dim3 ga(TT/64, NHEAD, KSPLIT);
  k_attn<<<ga, 256, 0, stream>>>(qhb, khb, vTb, seg, cu, pacc, plsum);

  int ncomb = TT*NHEAD*HDIM;
  k_combine<<<dim3((ncomb + 255)/256), 256, 0, stream>>>(pacc, plsum, aob);

  dim3 go(TT/64, DM/64);
  k_gemm_o<<<go, 256, 0, stream>>>(aob, wob, bo, (float*)d_out);
}

// Round 8
// 198.712 us; speedup vs baseline: 1.0875x; 1.0224x over previous
//
#include <hip/hip_runtime.h>

#define TT 2048
#define DM 1152
#define NHEAD 16
#define HDIM 72
#define HDP 96
#define HDV 80
#define KSPLIT 2

typedef __attribute__((ext_vector_type(8))) __bf16 bf16x8;
typedef __attribute__((ext_vector_type(4))) float f32x4;
typedef unsigned short u16;
typedef unsigned int u32;
typedef __attribute__((ext_vector_type(4))) u16 u16x4;

__device__ inline u16 f2bf(float f){
  u32 u = __builtin_bit_cast(u32, f);
  return (u16)((u + 0x7FFFu + ((u >> 16) & 1u)) >> 16);
}
__device__ inline float bf2f(u16 v){
  return __builtin_bit_cast(float, ((u32)v) << 16);
}
__device__ inline bf16x8 ldb8(const u16* p){
  uint4 u = *(const uint4*)p;
  return __builtin_bit_cast(bf16x8, u);
}
__device__ inline f32x4 mfma16(bf16x8 a, bf16x8 b, f32x4 c){
  return __builtin_amdgcn_mfma_f32_16x16x32_bf16(a, b, c, 0, 0, 0);
}
// async global->LDS, 16B per lane, dest = wave-uniform base + lane*16
__device__ inline void gload_lds16(const u16* g, u16* l){
  __builtin_amdgcn_global_load_lds(
      (const __attribute__((address_space(1))) void*)g,
      (__attribute__((address_space(3))) void*)l, 16, 0, 0);
}

// ---- fp32 -> bf16 conversion (float4-vectorized); segment ids; pad-zeroing ----
__global__ void k_convert(const float* hid, const float* wq, const float* wk,
                          const float* wv, const float* wo, const int* cu,
                          u16* hb, u16* wqb, u16* wkb, u16* wvb, u16* wob,
                          u16* qhb, u16* khb, int* seg)
{
  long i = (long)blockIdx.x * blockDim.x + threadIdx.x;
  const long NHID4 = (long)TT * DM / 4;      // 589824
  const long NW4 = (long)DM * DM / 4;        // 331776
  const long NC4 = NHID4 + 4*NW4;            // 1916928
  if (i < NC4) {
    const float4* src; u16* dst; long o;
    if (i < NHID4) { src = (const float4*)hid; dst = hb; o = i; }
    else {
      long j = i - NHID4;
      int w = (int)(j / NW4);
      o = j - (long)w * NW4;
      src = (const float4*)((w==0)?wq:(w==1)?wk:(w==2)?wv:wo);
      dst = (w==0)?wqb:(w==1)?wkb:(w==2)?wvb:wob;
    }
    float4 v = src[o];
    u16x4 r; r.x = f2bf(v.x); r.y = f2bf(v.y); r.z = f2bf(v.z); r.w = f2bf(v.w);
    *(u16x4*)(dst + o*4) = r;
  } else {
    // zero the dh padding (u16 cols 72..95 = u32 cols 36..47) of qhb/khb
    long j = i - NC4;                        // [0, 2*16*2048*12)
    const long PER = (long)NHEAD*TT*12;
    if (j < 2*PER) {
      int arr = (int)(j / PER);
      long r = j - (long)arr*PER;
      long th = r / 12;                      // h*TT + t
      int c = (int)(r - th*12);
      ((u32*)(arr ? khb : qhb))[th*48 + 36 + c] = 0u;
    }
  }
  if (i < TT) {
    int c = 0;
    for (int e = 0; e < 9; ++e) c += (cu[e] <= (int)i);
    seg[i] = c - 1;
  }
}

// ---- 128x64-tile double-buffered GEMM: C = (A(2048xK) @ W(NxK)^T + bias)*oscale ----
// mode 0: bf16 scatter to (H, T, 96);  mode 2: bf16 scatter to (H, 80, T)
__device__ __forceinline__ void gemm_m128n64(const u16* __restrict__ A,
                                             const u16* __restrict__ W,
                                             const float* __restrict__ bias,
                                             void* out, int mode, float oscale)
{
  __shared__ __align__(16) u16 As[2][128*32];   // 2 x 8 KB
  __shared__ __align__(16) u16 Bs[2][64*32];    // 2 x 4 KB
  int tid = threadIdx.x;
  int lane = tid & 63, wid = tid >> 6;
  int l15 = lane & 15, quad = lane >> 4;
  int bm = blockIdx.x * 128, bn = blockIdx.y * 64;
  int wm = wid*32;
  f32x4 acc[2][4] = {};
  const u16* ga = A + (long)(bm + (tid>>2))*DM + (tid&3)*8;
  const u16* gb = W + (long)(bn + (tid>>2))*DM + (tid&3)*8;
  // preload k-tile 0
  {
    u16* lA = As[0] + wid*512; u16* lB = Bs[0] + wid*512;
    gload_lds16(ga,          lA);
    gload_lds16(ga + 64*DM,  lA + 2048);
    gload_lds16(gb,          lB);
  }
  int cur = 0;
  for (int k0 = 0; k0 < DM; k0 += 32, cur ^= 1) {
    __syncthreads();                   // drains prefetch of buf[cur]
    if (k0 + 32 < DM) {                // prefetch next tile during compute
      u16* lA = As[cur^1] + wid*512; u16* lB = Bs[cur^1] + wid*512;
      gload_lds16(ga + k0 + 32,          lA);
      gload_lds16(ga + k0 + 32 + 64*DM,  lA + 2048);
      gload_lds16(gb + k0 + 32,          lB);
    }
    bf16x8 af[2], bfr[4];
    for (int i=0;i<2;i++) af[i]  = ldb8(As[cur] + (wm + i*16 + l15)*32 + quad*8);
    for (int i=0;i<4;i++) bfr[i] = ldb8(Bs[cur] + (i*16 + l15)*32 + quad*8);
    for (int mi=0;mi<2;mi++)
      for (int ni=0;ni<4;ni++)
        acc[mi][ni] = mfma16(af[mi], bfr[ni], acc[mi][ni]);
  }
  for (int ni=0;ni<4;ni++){
    int n = bn + ni*16 + l15;
    float bv_ = bias[n];
    int h = n / HDIM, dh = n - (n / HDIM)*HDIM;
    for (int mi=0;mi<2;mi++){
      int m0 = bm + wm + mi*16 + quad*4;
      for (int r=0;r<4;r++){
        float v = (acc[mi][ni][r] + bv_) * oscale;
        int m = m0 + r;
        if (mode == 0) {
          ((u16*)out)[((long)(h*TT + m))*HDP + dh] = f2bf(v);
        } else {
          ((u16*)out)[((long)(h*HDV + dh))*TT + m] = f2bf(v);
        }
      }
    }
  }
}

__global__ __launch_bounds__(256, 4) void k_gemm_qkv(const u16* __restrict__ A,
    const u16* __restrict__ Wq, const u16* __restrict__ Wk, const u16* __restrict__ Wv,
    const float* __restrict__ bq, const float* __restrict__ bk, const float* __restrict__ bv,
    u16* oq, u16* ok, u16* ov)
{
  const float scale = 0.11785113019775793f; // 72^-0.5, folded into q
  int z = blockIdx.z;
  if (z == 0)      gemm_m128n64(A, Wq, bq, oq, 0, scale);
  else if (z == 1) gemm_m128n64(A, Wk, bk, ok, 0, 1.0f);
  else             gemm_m128n64(A, Wv, bv, ov, 2, 1.0f);
}

// ---- O-projection: 64x64 tiles, double-buffered, fp32 out ----
__global__ __launch_bounds__(256, 4) void k_gemm_o(const u16* __restrict__ A,
    const u16* __restrict__ W, const float* __restrict__ bias, float* out)
{
  __shared__ __align__(16) u16 As[2][64*32];
  __shared__ __align__(16) u16 Bs[2][64*32];
  int tid = threadIdx.x;
  int lane = tid & 63, wid = tid >> 6;
  int l15 = lane & 15, quad = lane >> 4;
  int bm = blockIdx.x * 64, bn = blockIdx.y * 64;
  int wm = (wid>>1)*32, wn = (wid&1)*32;
  f32x4 acc[2][2] = {};
  const u16* ga = A + (long)(bm + (tid>>2))*DM + (tid&3)*8;
  const u16* gb = W + (long)(bn + (tid>>2))*DM + (tid&3)*8;
  {
    gload_lds16(ga, As[0] + wid*512);
    gload_lds16(gb, Bs[0] + wid*512);
  }
  int cur = 0;
  for (int k0 = 0; k0 < DM; k0 += 32, cur ^= 1) {
    __syncthreads();
    if (k0 + 32 < DM) {
      gload_lds16(ga + k0 + 32, As[cur^1] + wid*512);
      gload_lds16(gb + k0 + 32, Bs[cur^1] + wid*512);
    }
    bf16x8 af[2], bfr[2];
    for (int i=0;i<2;i++) af[i]  = ldb8(As[cur] + (wm + i*16 + l15)*32 + quad*8);
    for (int i=0;i<2;i++) bfr[i] = ldb8(Bs[cur] + (wn + i*16 + l15)*32 + quad*8);
    for (int mi=0;mi<2;mi++)
      for (int ni=0;ni<2;ni++)
        acc[mi][ni] = mfma16(af[mi], bfr[ni], acc[mi][ni]);
  }
  for (int ni=0;ni<2;ni++){
    int n = bn + wn + ni*16 + l15;
    float bv_ = bias[n];
    for (int mi=0;mi<2;mi++){
      int m0 = bm + wm + mi*16 + quad*4;
      for (int r=0;r<4;r++)
        out[(long)(m0 + r)*DM + n] = acc[mi][ni][r] + bv_;
    }
  }
}

// ---- RoPE in-place on q,k padded layouts ----
__global__ void k_rope(u16* qh, u16* kh, const float* __restrict__ cosb,
                       const float* __restrict__ sinb)
{
  int i = blockIdx.x * blockDim.x + threadIdx.x;
  const int total = 2 * NHEAD * TT * 36;
  if (i >= total) return;
  int d = i % 36; int rest = i / 36;
  int t = rest % TT; rest /= TT;
  int h = rest % NHEAD; int qk = rest / NHEAD;
  u16* base = (qk ? kh : qh) + ((long)h*TT + t)*HDP;
  float x1 = bf2f(base[d]), x2 = bf2f(base[d+36]);
  float c = cosb[t*HDIM + d], s = sinb[t*HDIM + d];
  base[d]    = f2bf(x1*c - x2*s);
  base[d+36] = f2bf(x2*c + x1*s);
}

// ---- flash attention: 128 q-rows/block (2 q-tiles per wave), LDS-staged K dbuf,
//      fixed-max softmax, split-K over blockIdx.z ----
__global__ __launch_bounds__(256, 2) void k_attn(const u16* __restrict__ qh,
                                                 const u16* __restrict__ kh,
                                                 const u16* __restrict__ vT,
                                                 const int* __restrict__ seg,
                                                 const int* __restrict__ cu,
                                                 float* __restrict__ pacc,
                                                 float* __restrict__ plsum)
{
  __shared__ __align__(16) u16 Ks[2][64*96];       // 2 x 12 KB double buffer
  __shared__ __align__(16) u16 pbuf[4][16][144];   // per-wave, 2 P-tiles (cols t*72+0..63)
  int h = blockIdx.y;
  int z = blockIdx.z;
  int tid = threadIdx.x, lane = tid & 63, wid = tid >> 6;
  int l15 = lane & 15, quad = lane >> 4;
  int qb0 = blockIdx.x * 128;
  int qbase = qb0 + wid*32;                        // wave's 32 q rows

  bf16x8 qf[2][3];
  int lo[2][4], hi[2][4];
  for (int t=0;t<2;t++){
    const u16* qp = qh + ((long)h*TT + qbase + t*16 + l15)*HDP + quad*8;
    qf[t][0] = ldb8(qp); qf[t][1] = ldb8(qp+32); qf[t][2] = ldb8(qp+64);
    for (int r=0;r<4;r++){
      int sq = seg[qbase + t*16 + quad*4 + r];
      lo[t][r] = cu[sq]; hi[t][r] = cu[sq+1];
    }
  }
  f32x4 acc[2][5] = {};
  float lsum[2][4] = {};

  int s_begin = cu[seg[qb0]] & ~63;
  int s_end = cu[seg[qb0 + 127] + 1];
  int nt = (s_end - s_begin + 63) >> 6;
  int nt0 = (nt + 1) >> 1;
  int it_lo = z ? nt0 : 0;
  int it_hi = z ? nt : nt0;

  const u16* kbase = kh + (long)h*TT*HDP;
  const u16* vbase = vT + ((long)h*HDV + l15)*TT + quad*8;

  if (it_lo < it_hi) {
    {
      const u16* gk = kbase + (long)(s_begin + it_lo*64)*HDP + tid*8;
      u16* lK = Ks[0] + wid*512;
      gload_lds16(gk,        lK);
      gload_lds16(gk + 2048, lK + 2048);
      gload_lds16(gk + 4096, lK + 4096);
    }
    for (int it = it_lo; it < it_hi; ++it) {
      int s0 = s_begin + it*64;
      int cur = (it - it_lo) & 1;
      __syncthreads();
      if (it + 1 < it_hi) {
        const u16* gk = kbase + (long)(s0 + 64)*HDP + tid*8;
        u16* lK = Ks[cur^1] + wid*512;
        gload_lds16(gk,        lK);
        gload_lds16(gk + 2048, lK + 2048);
        gload_lds16(gk + 4096, lK + 4096);
      }
      // QK^T: K frags shared by both q-tiles
      f32x4 sc[2][4] = {};
      for (int j=0;j<4;j++){
        const u16* kp = Ks[cur] + (j*16 + l15)*96 + quad*8;
        bf16x8 k0 = ldb8(kp), k1 = ldb8(kp+32), k2 = ldb8(kp+64);
        sc[0][j] = mfma16(qf[0][0], k0, sc[0][j]);
        sc[1][j] = mfma16(qf[1][0], k0, sc[1][j]);
        sc[0][j] = mfma16(qf[0][1], k1, sc[0][j]);
        sc[1][j] = mfma16(qf[1][1], k1, sc[1][j]);
        sc[0][j] = mfma16(qf[0][2], k2, sc[0][j]);
        sc[1][j] = mfma16(qf[1][2], k2, sc[1][j]);
      }
      // mask + exp + P write (tile t occupies cols [t*72, t*72+64) of pbuf row)
      for (int t=0;t<2;t++){
        for (int j=0;j<4;j++){
          int kidx = s0 + j*16 + l15;
          for (int r=0;r<4;r++){
            bool in = (kidx >= lo[t][r]) && (kidx < hi[t][r]);
            float p = in ? __expf(sc[t][j][r]) : 0.f;
            lsum[t][r] += p;
            pbuf[wid][quad*4+r][t*72 + j*16 + l15] = f2bf(p);
          }
        }
      }
      bf16x8 pf[2][2];
      for (int t=0;t<2;t++){
        pf[t][0] = ldb8(&pbuf[wid][l15][t*72 + quad*8]);
        pf[t][1] = ldb8(&pbuf[wid][l15][t*72 + 32 + quad*8]);
      }
      // PV: V frags shared by both q-tiles
      const u16* vp = vbase + s0;
      for (int n=0;n<5;n++){
        bf16x8 vf0 = ldb8(vp + (long)n*16*TT);
        bf16x8 vf1 = ldb8(vp + (long)n*16*TT + 32);
        acc[0][n] = mfma16(pf[0][0], vf0, acc[0][n]);
        acc[1][n] = mfma16(pf[1][0], vf0, acc[1][n]);
        acc[0][n] = mfma16(pf[0][1], vf1, acc[0][n]);
        acc[1][n] = mfma16(pf[1][1], vf1, acc[1][n]);
      }
    }
  }
  // reduce lsum across the 16 key-lanes
  for (int off=1; off<16; off<<=1)
    for (int t=0;t<2;t++)
      for (int r=0;r<4;r++)
        lsum[t][r] += __shfl_xor(lsum[t][r], off, 64);
  // write unnormalized partials
  for (int t=0;t<2;t++){
    for (int n=0;n<5;n++){
      int dh = n*16 + l15;
      for (int r=0;r<4;r++){
        int tk = qbase + t*16 + quad*4 + r;
        pacc[(((long)z*TT + tk)*NHEAD + h)*HDV + dh] = acc[t][n][r];
      }
    }
    if (l15 == 0){
      for (int r=0;r<4;r++){
        int tk = qbase + t*16 + quad*4 + r;
        plsum[((long)z*TT + tk)*NHEAD + h] = lsum[t][r];
      }
    }
  }
}

// ---- combine split-K partials -> aob (T, DM) bf16 ----
__global__ void k_combine(const float* __restrict__ pacc,
                          const float* __restrict__ plsum,
                          u16* __restrict__ ao)
{
  int i = blockIdx.x*blockDim.x + threadIdx.x;
  const int total = TT*NHEAD*HDIM;
  if (i >= total) return;
  int dh = i % HDIM; int rest = i / HDIM;
  int h = rest % NHEAD; int t = rest / NHEAD;
  long i0 = ((long)t*NHEAD + h)*HDV + dh;
  float a = pacc[i0] + pacc[(long)TT*NHEAD*HDV + i0];
  float l = plsum[t*NHEAD + h] + plsum[TT*NHEAD + t*NHEAD + h];
  ao[(long)t*DM + h*HDIM + dh] = f2bf(a / l);
}

extern "C" void kernel_launch(void* const* d_in, const int* in_sizes, int n_in,
                              void* d_out, int out_size, void* d_ws, size_t ws_size,
                              hipStream_t stream)
{
  const float* hid  = (const float*)d_in[0];
  const int*   cu   = (const int*)d_in[1];
  const float* cosb = (const float*)d_in[2];
  const float* sinb = (const float*)d_in[3];
  const float* wq   = (const float*)d_in[4];
  const float* bq   = (const float*)d_in[5];
  const float* wk   = (const float*)d_in[6];
  const float* bk   = (const float*)d_in[7];
  const float* wv   = (const float*)d_in[8];
  const float* bv   = (const float*)d_in[9];
  const float* wo   = (const float*)d_in[10];
  const float* bo   = (const float*)d_in[11];

  char* ws = (char*)d_ws;
  u16* hb  = (u16*)ws; ws += (long)TT*DM*2;
  u16* wqb = (u16*)ws; ws += (long)DM*DM*2;
  u16* wkb = (u16*)ws; ws += (long)DM*DM*2;
  u16* wvb = (u16*)ws; ws += (long)DM*DM*2;
  u16* wob = (u16*)ws; ws += (long)DM*DM*2;
  u16* qhb = (u16*)ws; ws += (long)NHEAD*TT*HDP*2;
  u16* khb = (u16*)ws; ws += (long)NHEAD*TT*HDP*2;
  u16* vTb = (u16*)ws; ws += (long)NHEAD*HDV*TT*2;
  u16* aob = (u16*)ws; ws += (long)TT*DM*2;
  int* seg = (int*)ws; ws += (long)TT*4;
  float* pacc  = (float*)ws; ws += (long)KSPLIT*TT*NHEAD*HDV*4;
  float* plsum = (float*)ws; ws += (long)KSPLIT*TT*NHEAD*4;

  long nconv = ((long)TT*DM + 4L*DM*DM)/4 + 2L*NHEAD*TT*12;
  k_convert<<<dim3((nconv + 255)/256), 256, 0, stream>>>(
      hid, wq, wk, wv, wo, cu, hb, wqb, wkb, wvb, wob, qhb, khb, seg);

  dim3 gqkv(TT/128, DM/64, 3);
  k_gemm_qkv<<<gqkv, 256, 0, stream>>>(hb, wqb, wkb, wvb, bq, bk, bv, qhb, khb, vTb);

  int nrope = 2*NHEAD*TT*36;
  k_rope<<<dim3((nrope + 255)/256), 256, 0, stream>>>(qhb, khb, cosb, sinb);

  dim3 ga(TT/128, NHEAD, KSPLIT);
  k_attn<<<ga, 256, 0, stream>>>(qhb, khb, vTb, seg, cu, pacc, plsum);

  int ncomb = TT*NHEAD*HDIM;
  k_combine<<<dim3((ncomb + 255)/256), 256, 0, stream>>>(pacc, plsum, aob);

  dim3 go(TT/64, DM/64);
  k_gemm_o<<<go, 256, 0, stream>>>(aob, wob, bo, (float*)d_out);
}

// Round 9
// 195.315 us; speedup vs baseline: 1.1064x; 1.0174x over previous
//
#include <hip/hip_runtime.h>

#define TT 2048
#define DM 1152
#define NHEAD 16
#define HDIM 72
#define HDP 96
#define HDV 80
#define KSPLIT 2

typedef __attribute__((ext_vector_type(8))) __bf16 bf16x8;
typedef __attribute__((ext_vector_type(4))) float f32x4;
typedef unsigned short u16;
typedef unsigned int u32;
typedef __attribute__((ext_vector_type(4))) u16 u16x4;

__device__ inline u16 f2bf(float f){
  u32 u = __builtin_bit_cast(u32, f);
  return (u16)((u + 0x7FFFu + ((u >> 16) & 1u)) >> 16);
}
__device__ inline float bf2f(u16 v){
  return __builtin_bit_cast(float, ((u32)v) << 16);
}
__device__ inline bf16x8 ldb8(const u16* p){
  uint4 u = *(const uint4*)p;
  return __builtin_bit_cast(bf16x8, u);
}
__device__ inline f32x4 mfma16(bf16x8 a, bf16x8 b, f32x4 c){
  return __builtin_amdgcn_mfma_f32_16x16x32_bf16(a, b, c, 0, 0, 0);
}
// async global->LDS, 16B per lane, dest = wave-uniform base + lane*16
__device__ inline void gload_lds16(const u16* g, u16* l){
  __builtin_amdgcn_global_load_lds(
      (const __attribute__((address_space(1))) void*)g,
      (__attribute__((address_space(3))) void*)l, 16, 0, 0);
}

// ---- fp32 -> bf16 conversion (float4-vectorized); segment ids; pad-zeroing ----
__global__ void k_convert(const float* hid, const float* wq, const float* wk,
                          const float* wv, const float* wo, const int* cu,
                          u16* hb, u16* wqb, u16* wkb, u16* wvb, u16* wob,
                          u16* qhb, u16* khb, int* seg)
{
  long i = (long)blockIdx.x * blockDim.x + threadIdx.x;
  const long NHID4 = (long)TT * DM / 4;      // 589824
  const long NW4 = (long)DM * DM / 4;        // 331776
  const long NC4 = NHID4 + 4*NW4;            // 1916928
  if (i < NC4) {
    const float4* src; u16* dst; long o;
    if (i < NHID4) { src = (const float4*)hid; dst = hb; o = i; }
    else {
      long j = i - NHID4;
      int w = (int)(j / NW4);
      o = j - (long)w * NW4;
      src = (const float4*)((w==0)?wq:(w==1)?wk:(w==2)?wv:wo);
      dst = (w==0)?wqb:(w==1)?wkb:(w==2)?wvb:wob;
    }
    float4 v = src[o];
    u16x4 r; r.x = f2bf(v.x); r.y = f2bf(v.y); r.z = f2bf(v.z); r.w = f2bf(v.w);
    *(u16x4*)(dst + o*4) = r;
  } else {
    // zero the dh padding (u16 cols 72..95 = u32 cols 36..47) of qhb/khb
    long j = i - NC4;                        // [0, 2*16*2048*12)
    const long PER = (long)NHEAD*TT*12;
    if (j < 2*PER) {
      int arr = (int)(j / PER);
      long r = j - (long)arr*PER;
      long th = r / 12;                      // h*TT + t
      int c = (int)(r - th*12);
      ((u32*)(arr ? khb : qhb))[th*48 + 36 + c] = 0u;
    }
  }
  if (i < TT) {
    int c = 0;
    for (int e = 0; e < 9; ++e) c += (cu[e] <= (int)i);
    seg[i] = c - 1;
  }
}

// ---- 128x64-tile double-buffered GEMM: C = (A(2048xK) @ W(NxK)^T + bias)*oscale ----
// mode 0: bf16 scatter to (H, T, 96);  mode 2: bf16 scatter to (H, 80, T)
__device__ __forceinline__ void gemm_m128n64(const u16* __restrict__ A,
                                             const u16* __restrict__ W,
                                             const float* __restrict__ bias,
                                             void* out, int mode, float oscale)
{
  __shared__ __align__(16) u16 As[2][128*32];   // 2 x 8 KB
  __shared__ __align__(16) u16 Bs[2][64*32];    // 2 x 4 KB
  int tid = threadIdx.x;
  int lane = tid & 63, wid = tid >> 6;
  int l15 = lane & 15, quad = lane >> 4;
  int bm = blockIdx.x * 128, bn = blockIdx.y * 64;
  int wm = wid*32;
  f32x4 acc[2][4] = {};
  const u16* ga = A + (long)(bm + (tid>>2))*DM + (tid&3)*8;
  const u16* gb = W + (long)(bn + (tid>>2))*DM + (tid&3)*8;
  // preload k-tile 0
  {
    u16* lA = As[0] + wid*512; u16* lB = Bs[0] + wid*512;
    gload_lds16(ga,          lA);
    gload_lds16(ga + 64*DM,  lA + 2048);
    gload_lds16(gb,          lB);
  }
  int cur = 0;
  for (int k0 = 0; k0 < DM; k0 += 32, cur ^= 1) {
    __syncthreads();                   // drains prefetch of buf[cur]
    if (k0 + 32 < DM) {                // prefetch next tile during compute
      u16* lA = As[cur^1] + wid*512; u16* lB = Bs[cur^1] + wid*512;
      gload_lds16(ga + k0 + 32,          lA);
      gload_lds16(ga + k0 + 32 + 64*DM,  lA + 2048);
      gload_lds16(gb + k0 + 32,          lB);
    }
    bf16x8 af[2], bfr[4];
    for (int i=0;i<2;i++) af[i]  = ldb8(As[cur] + (wm + i*16 + l15)*32 + quad*8);
    for (int i=0;i<4;i++) bfr[i] = ldb8(Bs[cur] + (i*16 + l15)*32 + quad*8);
    for (int mi=0;mi<2;mi++)
      for (int ni=0;ni<4;ni++)
        acc[mi][ni] = mfma16(af[mi], bfr[ni], acc[mi][ni]);
  }
  for (int ni=0;ni<4;ni++){
    int n = bn + ni*16 + l15;
    float bv_ = bias[n];
    int h = n / HDIM, dh = n - (n / HDIM)*HDIM;
    for (int mi=0;mi<2;mi++){
      int m0 = bm + wm + mi*16 + quad*4;
      for (int r=0;r<4;r++){
        float v = (acc[mi][ni][r] + bv_) * oscale;
        int m = m0 + r;
        if (mode == 0) {
          ((u16*)out)[((long)(h*TT + m))*HDP + dh] = f2bf(v);
        } else {
          ((u16*)out)[((long)(h*HDV + dh))*TT + m] = f2bf(v);
        }
      }
    }
  }
}

__global__ __launch_bounds__(256, 4) void k_gemm_qkv(const u16* __restrict__ A,
    const u16* __restrict__ Wq, const u16* __restrict__ Wk, const u16* __restrict__ Wv,
    const float* __restrict__ bq, const float* __restrict__ bk, const float* __restrict__ bv,
    u16* oq, u16* ok, u16* ov)
{
  const float scale = 0.11785113019775793f; // 72^-0.5, folded into q
  int z = blockIdx.z;
  if (z == 0)      gemm_m128n64(A, Wq, bq, oq, 0, scale);
  else if (z == 1) gemm_m128n64(A, Wk, bk, ok, 0, 1.0f);
  else             gemm_m128n64(A, Wv, bv, ov, 2, 1.0f);
}

// ---- O-projection: 64x64 tiles, double-buffered, fp32 out ----
__global__ __launch_bounds__(256, 4) void k_gemm_o(const u16* __restrict__ A,
    const u16* __restrict__ W, const float* __restrict__ bias, float* out)
{
  __shared__ __align__(16) u16 As[2][64*32];
  __shared__ __align__(16) u16 Bs[2][64*32];
  int tid = threadIdx.x;
  int lane = tid & 63, wid = tid >> 6;
  int l15 = lane & 15, quad = lane >> 4;
  int bm = blockIdx.x * 64, bn = blockIdx.y * 64;
  int wm = (wid>>1)*32, wn = (wid&1)*32;
  f32x4 acc[2][2] = {};
  const u16* ga = A + (long)(bm + (tid>>2))*DM + (tid&3)*8;
  const u16* gb = W + (long)(bn + (tid>>2))*DM + (tid&3)*8;
  {
    gload_lds16(ga, As[0] + wid*512);
    gload_lds16(gb, Bs[0] + wid*512);
  }
  int cur = 0;
  for (int k0 = 0; k0 < DM; k0 += 32, cur ^= 1) {
    __syncthreads();
    if (k0 + 32 < DM) {
      gload_lds16(ga + k0 + 32, As[cur^1] + wid*512);
      gload_lds16(gb + k0 + 32, Bs[cur^1] + wid*512);
    }
    bf16x8 af[2], bfr[2];
    for (int i=0;i<2;i++) af[i]  = ldb8(As[cur] + (wm + i*16 + l15)*32 + quad*8);
    for (int i=0;i<2;i++) bfr[i] = ldb8(Bs[cur] + (wn + i*16 + l15)*32 + quad*8);
    for (int mi=0;mi<2;mi++)
      for (int ni=0;ni<2;ni++)
        acc[mi][ni] = mfma16(af[mi], bfr[ni], acc[mi][ni]);
  }
  for (int ni=0;ni<2;ni++){
    int n = bn + wn + ni*16 + l15;
    float bv_ = bias[n];
    for (int mi=0;mi<2;mi++){
      int m0 = bm + wm + mi*16 + quad*4;
      for (int r=0;r<4;r++)
        out[(long)(m0 + r)*DM + n] = acc[mi][ni][r] + bv_;
    }
  }
}

// ---- RoPE in-place on q,k padded layouts ----
__global__ void k_rope(u16* qh, u16* kh, const float* __restrict__ cosb,
                       const float* __restrict__ sinb)
{
  int i = blockIdx.x * blockDim.x + threadIdx.x;
  const int total = 2 * NHEAD * TT * 36;
  if (i >= total) return;
  int d = i % 36; int rest = i / 36;
  int t = rest % TT; rest /= TT;
  int h = rest % NHEAD; int qk = rest / NHEAD;
  u16* base = (qk ? kh : qh) + ((long)h*TT + t)*HDP;
  float x1 = bf2f(base[d]), x2 = bf2f(base[d+36]);
  float c = cosb[t*HDIM + d], s = sinb[t*HDIM + d];
  base[d]    = f2bf(x1*c - x2*s);
  base[d+36] = f2bf(x2*c + x1*s);
}

// ---- flash attention v3: BARRIER-FREE + in-place register prefetch of K ----
// 128 q-rows/block (2 q-tiles/wave), K frags in regs prefetched 1 tile ahead,
// V loads issued early (covered by softmax), pbuf wave-private. Split-K over z.
__global__ __launch_bounds__(256, 2) void k_attn(const u16* __restrict__ qh,
                                                 const u16* __restrict__ kh,
                                                 const u16* __restrict__ vT,
                                                 const int* __restrict__ seg,
                                                 const int* __restrict__ cu,
                                                 float* __restrict__ pacc,
                                                 float* __restrict__ plsum)
{
  __shared__ __align__(16) u16 pbuf[4][16][144];   // per-wave, 2 P-tiles (cols t*72+0..63)
  int h = blockIdx.y;
  int z = blockIdx.z;
  int tid = threadIdx.x, lane = tid & 63, wid = tid >> 6;
  int l15 = lane & 15, quad = lane >> 4;
  int qb0 = blockIdx.x * 128;
  int qbase = qb0 + wid*32;                        // wave's 32 q rows

  bf16x8 qf[2][3];
  int lo[2][4], hi[2][4];
  for (int t=0;t<2;t++){
    const u16* qp = qh + ((long)h*TT + qbase + t*16 + l15)*HDP + quad*8;
    qf[t][0] = ldb8(qp); qf[t][1] = ldb8(qp+32); qf[t][2] = ldb8(qp+64);
    for (int r=0;r<4;r++){
      int sq = seg[qbase + t*16 + quad*4 + r];
      lo[t][r] = cu[sq]; hi[t][r] = cu[sq+1];
    }
  }
  f32x4 acc[2][5] = {};
  float lsum[2][4] = {};

  int s_begin = cu[seg[qb0]] & ~63;
  int s_end = cu[seg[qb0 + 127] + 1];
  int nt = (s_end - s_begin + 63) >> 6;
  int nt0 = (nt + 1) >> 1;
  int it_lo = z ? nt0 : 0;
  int it_hi = z ? nt : nt0;

  const u16* kbase = kh + (long)h*TT*HDP;
  const u16* vbase = vT + ((long)h*HDV + l15)*TT + quad*8;

  if (it_lo < it_hi) {
    // preload K frags for first tile: B[n=key, k=dh], 12 x 16B per lane
    bf16x8 kf[4][3];
    {
      const u16* kp = kbase + (long)(s_begin + it_lo*64 + l15)*HDP + quad*8;
      for (int j=0;j<4;j++)
        for (int c=0;c<3;c++)
          kf[j][c] = ldb8(kp + j*16*HDP + c*32);
    }
    for (int it = it_lo; it < it_hi; ++it) {
      int s0 = s_begin + it*64;
      // QK^T with current K frags (shared by both q-tiles)
      f32x4 sc[2][4] = {};
      for (int j=0;j<4;j++){
        sc[0][j] = mfma16(qf[0][0], kf[j][0], sc[0][j]);
        sc[1][j] = mfma16(qf[1][0], kf[j][0], sc[1][j]);
        sc[0][j] = mfma16(qf[0][1], kf[j][1], sc[0][j]);
        sc[1][j] = mfma16(qf[1][1], kf[j][1], sc[1][j]);
        sc[0][j] = mfma16(qf[0][2], kf[j][2], sc[0][j]);
        sc[1][j] = mfma16(qf[1][2], kf[j][2], sc[1][j]);
      }
      // V loads for THIS tile — issued early, covered by softmax below
      const u16* vp = vbase + s0;
      bf16x8 vf[5][2];
      for (int n=0;n<5;n++){
        vf[n][0] = ldb8(vp + (long)n*16*TT);
        vf[n][1] = ldb8(vp + (long)n*16*TT + 32);
      }
      // in-place prefetch of NEXT tile's K frags (used next iteration;
      // latency covered by softmax + pbuf + PV of this tile)
      if (it + 1 < it_hi) {
        const u16* kp = kbase + (long)(s0 + 64 + l15)*HDP + quad*8;
        for (int j=0;j<4;j++)
          for (int c=0;c<3;c++)
            kf[j][c] = ldb8(kp + j*16*HDP + c*32);
      }
      // mask + exp + P write (tile t occupies cols [t*72, t*72+64) of pbuf row)
      for (int t=0;t<2;t++){
        for (int j=0;j<4;j++){
          int kidx = s0 + j*16 + l15;
          for (int r=0;r<4;r++){
            bool in = (kidx >= lo[t][r]) && (kidx < hi[t][r]);
            float p = in ? __expf(sc[t][j][r]) : 0.f;
            lsum[t][r] += p;
            pbuf[wid][quad*4+r][t*72 + j*16 + l15] = f2bf(p);
          }
        }
      }
      bf16x8 pf[2][2];
      for (int t=0;t<2;t++){
        pf[t][0] = ldb8(&pbuf[wid][l15][t*72 + quad*8]);
        pf[t][1] = ldb8(&pbuf[wid][l15][t*72 + 32 + quad*8]);
      }
      // PV: V frags shared by both q-tiles
      for (int n=0;n<5;n++){
        acc[0][n] = mfma16(pf[0][0], vf[n][0], acc[0][n]);
        acc[1][n] = mfma16(pf[1][0], vf[n][0], acc[1][n]);
        acc[0][n] = mfma16(pf[0][1], vf[n][1], acc[0][n]);
        acc[1][n] = mfma16(pf[1][1], vf[n][1], acc[1][n]);
      }
    }
  }
  // reduce lsum across the 16 key-lanes
  for (int off=1; off<16; off<<=1)
    for (int t=0;t<2;t++)
      for (int r=0;r<4;r++)
        lsum[t][r] += __shfl_xor(lsum[t][r], off, 64);
  // write unnormalized partials
  for (int t=0;t<2;t++){
    for (int n=0;n<5;n++){
      int dh = n*16 + l15;
      for (int r=0;r<4;r++){
        int tk = qbase + t*16 + quad*4 + r;
        pacc[(((long)z*TT + tk)*NHEAD + h)*HDV + dh] = acc[t][n][r];
      }
    }
    if (l15 == 0){
      for (int r=0;r<4;r++){
        int tk = qbase + t*16 + quad*4 + r;
        plsum[((long)z*TT + tk)*NHEAD + h] = lsum[t][r];
      }
    }
  }
}

// ---- combine split-K partials -> aob (T, DM) bf16 ----
__global__ void k_combine(const float* __restrict__ pacc,
                          const float* __restrict__ plsum,
                          u16* __restrict__ ao)
{
  int i = blockIdx.x*blockDim.x + threadIdx.x;
  const int total = TT*NHEAD*HDIM;
  if (i >= total) return;
  int dh = i % HDIM; int rest = i / HDIM;
  int h = rest % NHEAD; int t = rest / NHEAD;
  long i0 = ((long)t*NHEAD + h)*HDV + dh;
  float a = pacc[i0] + pacc[(long)TT*NHEAD*HDV + i0];
  float l = plsum[t*NHEAD + h] + plsum[TT*NHEAD + t*NHEAD + h];
  ao[(long)t*DM + h*HDIM + dh] = f2bf(a / l);
}

extern "C" void kernel_launch(void* const* d_in, const int* in_sizes, int n_in,
                              void* d_out, int out_size, void* d_ws, size_t ws_size,
                              hipStream_t stream)
{
  const float* hid  = (const float*)d_in[0];
  const int*   cu   = (const int*)d_in[1];
  const float* cosb = (const float*)d_in[2];
  const float* sinb = (const float*)d_in[3];
  const float* wq   = (const float*)d_in[4];
  const float* bq   = (const float*)d_in[5];
  const float* wk   = (const float*)d_in[6];
  const float* bk   = (const float*)d_in[7];
  const float* wv   = (const float*)d_in[8];
  const float* bv   = (const float*)d_in[9];
  const float* wo   = (const float*)d_in[10];
  const float* bo   = (const float*)d_in[11];

  char* ws = (char*)d_ws;
  u16* hb  = (u16*)ws; ws += (long)TT*DM*2;
  u16* wqb = (u16*)ws; ws += (long)DM*DM*2;
  u16* wkb = (u16*)ws; ws += (long)DM*DM*2;
  u16* wvb = (u16*)ws; ws += (long)DM*DM*2;
  u16* wob = (u16*)ws; ws += (long)DM*DM*2;
  u16* qhb = (u16*)ws; ws += (long)NHEAD*TT*HDP*2;
  u16* khb = (u16*)ws; ws += (long)NHEAD*TT*HDP*2;
  u16* vTb = (u16*)ws; ws += (long)NHEAD*HDV*TT*2;
  u16* aob = (u16*)ws; ws += (long)TT*DM*2;
  int* seg = (int*)ws; ws += (long)TT*4;
  float* pacc  = (float*)ws; ws += (long)KSPLIT*TT*NHEAD*HDV*4;
  float* plsum = (float*)ws; ws += (long)KSPLIT*TT*NHEAD*4;

  long nconv = ((long)TT*DM + 4L*DM*DM)/4 + 2L*NHEAD*TT*12;
  k_convert<<<dim3((nconv + 255)/256), 256, 0, stream>>>(
      hid, wq, wk, wv, wo, cu, hb, wqb, wkb, wvb, wob, qhb, khb, seg);

  dim3 gqkv(TT/128, DM/64, 3);
  k_gemm_qkv<<<gqkv, 256, 0, stream>>>(hb, wqb, wkb, wvb, bq, bk, bv, qhb, khb, vTb);

  int nrope = 2*NHEAD*TT*36;
  k_rope<<<dim3((nrope + 255)/256), 256, 0, stream>>>(qhb, khb, cosb, sinb);

  dim3 ga(TT/128, NHEAD, KSPLIT);
  k_attn<<<ga, 256, 0, stream>>>(qhb, khb, vTb, seg, cu, pacc, plsum);

  int ncomb = TT*NHEAD*HDIM;
  k_combine<<<dim3((ncomb + 255)/256), 256, 0, stream>>>(pacc, plsum, aob);

  dim3 go(TT/64, DM/64);
  k_gemm_o<<<go, 256, 0, stream>>>(aob, wob, bo, (float*)d_out);
}